// Round 7
// baseline (996.188 us; speedup 1.0000x reference)
//
#include <hip/hip_runtime.h>
#include <hip/hip_bf16.h>
#include <math.h>

#define MDIM 32768
#define NDIM 2048
#define KDIM 2048

typedef __attribute__((ext_vector_type(8))) short bf16x8;
typedef __attribute__((ext_vector_type(4))) float f32x4;

__device__ __forceinline__ unsigned short f2bf(float f) {
  unsigned int u = __float_as_uint(f);
  u += 0x7FFFu + ((u >> 16) & 1u);
  return (unsigned short)(u >> 16);
}
__device__ __forceinline__ float bf2f(unsigned short b) {
  return __uint_as_float(((unsigned int)b) << 16);
}

__device__ __forceinline__ void gll16(const void* g, void* l) {
  __builtin_amdgcn_global_load_lds((__attribute__((address_space(1))) void*)g,
                                   (__attribute__((address_space(3))) void*)l,
                                   16, 0, 0);
}

// ---------------- split x into bf16 hi/lo ----------------
__global__ void split_x_kernel(const float4* __restrict__ x, ushort4* __restrict__ xhi,
                               ushort4* __restrict__ xlo, int n4) {
  int stride = gridDim.x * blockDim.x;
  for (int i = blockIdx.x * blockDim.x + threadIdx.x; i < n4; i += stride) {
    float4 v = x[i];
    ushort4 h, l;
    h.x = f2bf(v.x); l.x = f2bf(v.x - bf2f(h.x));
    h.y = f2bf(v.y); l.y = f2bf(v.y - bf2f(h.y));
    h.z = f2bf(v.z); l.z = f2bf(v.z - bf2f(h.z));
    h.w = f2bf(v.w); l.w = f2bf(v.w - bf2f(h.w));
    xhi[i] = h; xlo[i] = l;
  }
}

// ---------------- transpose + split W1 -> WT (N x K) hi/lo ----------------
__global__ void split_wT_kernel(const float* __restrict__ w1, unsigned short* __restrict__ wthi,
                                unsigned short* __restrict__ wtlo) {
  __shared__ float tile[32][33];
  int bx = blockIdx.x, by = blockIdx.y;
  int tx = threadIdx.x, ty = threadIdx.y;  // (32, 8)
#pragma unroll
  for (int r = 0; r < 4; ++r) {
    int d = by * 32 + ty + r * 8;
    tile[ty + r * 8][tx] = w1[(size_t)d * NDIM + bx * 32 + tx];
  }
  __syncthreads();
#pragma unroll
  for (int r = 0; r < 4; ++r) {
    int h = bx * 32 + ty + r * 8;
    float v = tile[tx][ty + r * 8];
    unsigned short hi = f2bf(v);
    unsigned short lo = f2bf(v - bf2f(hi));
    size_t o = (size_t)h * KDIM + by * 32 + tx;
    wthi[o] = hi; wtlo[o] = lo;
  }
}

// ---------------- fused GEMM: 2 phases/tile, 32 MFMA each ----------------
// logits[m] = sum_n relu(sum_k x[m,k] W1[k,n] + b1[n]) * W2[n]
// 3-product split folded into 96 K-tiles of 64:
//   kt 0..31: xhi*wthi ; 32..63: xhi*wtlo ; 64..95: xlo*wthi
// BM=BN=256, BK=64, 8 waves. LDS ring = 8 half-tile slots (16 KB, swizzled).
// Half-tile stream per tile: [A0,B0,B1,A1]. Per tile TWO phases:
//   P0: MFMA Q00(a=A0 x b0f) + Q01(a x b1f); stage h+8,h+9; fill a<-A1
//   P1: MFMA Q11(a=A1 x b1f) + Q10(a x b0f); stage h+10,h+11;
//       fill a<-A0', b0f<-B0', b1f<-B1'
// WAITBAR = vmcnt(6) [fills read only landed slots: at each barrier every
// wave has landed through issued-3 half-tiles] + lgkmcnt(0) [slot overwrite
// is 1 barrier after its last ds_read; drain forces all waves' reads
// serviced before any wave crosses and issues the overwriting gll16].
// PROLOGUE uses TWO barriers: vmcnt is PER-WAVE, and each slot is written
// cooperatively by all 8 waves, so fragment reads must come after a barrier
// (cross-wave landing), and a second lgkmcnt(0)+barrier protects the reads
// from the first loop STAGE overwrite (round-5/6 NaN was this race).
__global__ __launch_bounds__(512, 2) void gemm8(
    const unsigned short* __restrict__ xhi, const unsigned short* __restrict__ xlo,
    const unsigned short* __restrict__ wthi, const unsigned short* __restrict__ wtlo,
    const float* __restrict__ b1, const float* __restrict__ w2,
    float* __restrict__ part) {
  __shared__ char lds[8 * 16384];   // 128 KiB ring

  const int t = threadIdx.x;
  const int l = t & 63;
  const int w = t >> 6;
  const int sub_m = w >> 2, sub_n = w & 3;
  const int r16 = l & 15;
  const int q4 = l >> 4;

  // XCD-chunked bijective swizzle: 1024 blocks = 8 XCDs x 128
  int bid = blockIdx.x;
  int id = (bid & 7) * 128 + (bid >> 3);
  const int bm = id >> 3, bn = id & 7;
  const int m0 = bm * 256, n0 = bn * 256;

  // staging per-thread constants
  const int tr = t >> 3;                                  // 0..63
  const int cs16 = (((t & 7) ^ ((t >> 3) & 7)) << 4);     // swizzled chunk byte
  const int t16 = t << 4;

  // read-side per-thread constants
  const int axor = (l & 7) << 4;
  const int akoff = ((l >> 4) & 3) << 4;
  const int a_row0 = sub_m * 64 + (l & 15);
  const int b_row0 = sub_n * 32 + (l & 15);

#define STAGE(nn)                                                              \
  {                                                                            \
    int n_ = (nn);                                                             \
    if (n_ < 384) {                                                            \
      int jt = n_ >> 2, pos = n_ & 3;                                          \
      bool isA = (pos == 0) || (pos == 3);                                     \
      int hh = (pos >= 2) ? 1 : 0;                                             \
      const unsigned short* base =                                             \
          isA ? ((jt < 64) ? xhi : xlo)                                        \
              : ((jt < 32 || jt >= 64) ? wthi : wtlo);                         \
      int k0 = (jt & 31) << 6;                                                 \
      int row0 = (isA ? m0 : n0) + (hh << 7);                                  \
      char* dst = lds + ((n_ & 7) << 14) + t16;                                \
      const char* src = (const char*)base +                                    \
          ((((size_t)(row0 + tr)) << 11) + (size_t)k0) * 2 + cs16;             \
      gll16(src, dst);                                                         \
      gll16(src + (64ull << 12), dst + 8192);                                  \
    }                                                                          \
  }

#define LDA(slot)                                                              \
  _Pragma("unroll")                                                            \
  for (int fm = 0; fm < 4; ++fm)                                               \
    _Pragma("unroll")                                                          \
    for (int kk = 0; kk < 2; ++kk)                                             \
      a[fm][kk] = *(const bf16x8*)(lds + ((slot) << 14) +                      \
          (a_row0 + fm * 16) * 128 + (((kk << 6) | akoff) ^ axor));

#define LDB(dst, slot)                                                         \
  _Pragma("unroll")                                                            \
  for (int fn = 0; fn < 2; ++fn)                                               \
    _Pragma("unroll")                                                          \
    for (int kk = 0; kk < 2; ++kk)                                             \
      dst[fn][kk] = *(const bf16x8*)(lds + ((slot) << 14) +                    \
          (b_row0 + fn * 16) * 128 + (((kk << 6) | akoff) ^ axor));

#define MFMA16(accq, bb)                                                       \
  _Pragma("unroll")                                                            \
  for (int fm = 0; fm < 4; ++fm)                                               \
    _Pragma("unroll")                                                          \
    for (int fn = 0; fn < 2; ++fn) {                                           \
      accq[fm][fn] = __builtin_amdgcn_mfma_f32_16x16x32_bf16(a[fm][0], bb[fn][0], accq[fm][fn], 0, 0, 0); \
      accq[fm][fn] = __builtin_amdgcn_mfma_f32_16x16x32_bf16(a[fm][1], bb[fn][1], accq[fm][fn], 0, 0, 0); \
    }

#define WAITBAR                                                                \
  asm volatile("s_waitcnt vmcnt(6) lgkmcnt(0)" ::: "memory");                  \
  __builtin_amdgcn_s_barrier();                                                \
  asm volatile("" ::: "memory");

  f32x4 acc00[4][2], acc01[4][2], acc11[4][2], acc10[4][2];
  f32x4 zero = {0.f, 0.f, 0.f, 0.f};
#pragma unroll
  for (int i = 0; i < 4; ++i)
#pragma unroll
    for (int j = 0; j < 2; ++j) {
      acc00[i][j] = zero; acc01[i][j] = zero;
      acc11[i][j] = zero; acc10[i][j] = zero;
    }

  bf16x8 a[4][2], b0f[2][2], b1f[2][2];

  // prologue: stage H0..H7 (16 loads/wave); vmcnt(6) -> own halves 0..4
  // landed; BARRIER 1 -> ALL waves' halves 0..4 landed (cross-wave);
  // read initial fragments (slots 0,1,2); lgkmcnt(0) -> reads serviced;
  // BARRIER 2 -> no wave can start loop STAGEs (which overwrite slots 0,1)
  // until every wave's reads are done.
  STAGE(0); STAGE(1); STAGE(2); STAGE(3);
  STAGE(4); STAGE(5); STAGE(6); STAGE(7);
  asm volatile("s_waitcnt vmcnt(6)" ::: "memory");
  __builtin_amdgcn_s_barrier();
  asm volatile("" ::: "memory");
  LDA(0);          // A0 of tile 0
  LDB(b0f, 1);     // B0 of tile 0
  LDB(b1f, 2);     // B1 of tile 0
  asm volatile("s_waitcnt lgkmcnt(0)" ::: "memory");
  __builtin_amdgcn_s_barrier();
  asm volatile("" ::: "memory");

  for (int kt = 0; kt < 96; ++kt) {
    const int sb = (kt & 1) << 2;
    const int g0 = 4 * kt;
    // P0: Q00 + Q01 on A0; stage h+8,h+9; fill a <- A1 (slot sb+3)
    STAGE(g0 + 8);
    STAGE(g0 + 9);
    __builtin_amdgcn_s_setprio(1);
    MFMA16(acc00, b0f);
    MFMA16(acc01, b1f);
    __builtin_amdgcn_s_setprio(0);
    LDA(sb + 3);
    WAITBAR;
    // P1: Q11 + Q10 on A1; stage h+10,h+11; fill a,b0f,b1f for next tile
    STAGE(g0 + 10);
    STAGE(g0 + 11);
    __builtin_amdgcn_s_setprio(1);
    MFMA16(acc11, b1f);
    MFMA16(acc10, b0f);
    __builtin_amdgcn_s_setprio(0);
    LDA((sb + 4) & 7);
    LDB(b0f, (sb + 5) & 7);
    LDB(b1f, (sb + 6) & 7);
    WAITBAR;
  }

  // drain all staging before reusing LDS
  asm volatile("s_waitcnt vmcnt(0) lgkmcnt(0)" ::: "memory");
  __builtin_amdgcn_s_barrier();
  asm volatile("" ::: "memory");

  // epilogue: relu(acc + b1) * w2, reduce over n
  float b1v[2][2], w2v[2][2];
#pragma unroll
  for (int nh = 0; nh < 2; ++nh)
#pragma unroll
    for (int fn = 0; fn < 2; ++fn) {
      int n = n0 + nh * 128 + sub_n * 32 + fn * 16 + r16;
      b1v[nh][fn] = b1[n];
      w2v[nh][fn] = w2[n];
    }

  float* red = (float*)lds;   // 4 x 256 floats
#pragma unroll
  for (int mh = 0; mh < 2; ++mh)
#pragma unroll
    for (int fm = 0; fm < 4; ++fm)
#pragma unroll
      for (int j = 0; j < 4; ++j) {
        float s = 0.f;
#pragma unroll
        for (int fn = 0; fn < 2; ++fn) {
          float h0 = (mh == 0 ? acc00[fm][fn][j] : acc10[fm][fn][j]) + b1v[0][fn];
          s += fmaxf(h0, 0.f) * w2v[0][fn];
          float h1 = (mh == 0 ? acc01[fm][fn][j] : acc11[fm][fn][j]) + b1v[1][fn];
          s += fmaxf(h1, 0.f) * w2v[1][fn];
        }
        s += __shfl_xor(s, 1);
        s += __shfl_xor(s, 2);
        s += __shfl_xor(s, 4);
        s += __shfl_xor(s, 8);
        if (r16 == 0)
          red[sub_n * 256 + mh * 128 + sub_m * 64 + fm * 16 + q4 * 4 + j] = s;
      }
  __syncthreads();
  if (t < 256) {
    float p = red[t] + red[256 + t] + red[512 + t] + red[768 + t];
    part[(size_t)(m0 + t) * 8 + bn] = p;
  }
#undef STAGE
#undef LDA
#undef LDB
#undef MFMA16
#undef WAITBAR
}

// ---------------- per-batch-row: expected_k, top-k mask ----------------
// Reads the 8 per-N-tile partials directly (reduce_part folded in).
__global__ void rowstats(const float* __restrict__ part, const float* __restrict__ b2,
                         float* __restrict__ mask_out, float* __restrict__ ek_out) {
  __shared__ float vals[2048];
  __shared__ float srt[2048];
  __shared__ float redf[256];
  __shared__ int redi[256];
  int b = blockIdx.x, t = threadIdx.x;
  float b2v = b2[0];
  float psum = 0.f;
  for (int i = t; i < 2048; i += 256) {
    const float* pp = part + ((size_t)b * 2048 + i) * 8;
    float v = pp[0] + pp[1] + pp[2] + pp[3] + pp[4] + pp[5] + pp[6] + pp[7] + b2v;
    vals[i] = v; srt[i] = v;
    psum += 1.f / (1.f + expf(-v));
  }
  redf[t] = psum;
  __syncthreads();
  for (int s = 128; s > 0; s >>= 1) {
    if (t < s) redf[t] += redf[t + s];
    __syncthreads();
  }
  float ek = redf[0];
  int k = (int)ek;
  if (k < 32) k = 32;
  if (k > 2048) k = 2048;
  if (t == 0) ek_out[b] = ek;

  for (int ksz = 2; ksz <= 2048; ksz <<= 1) {
    for (int j = ksz >> 1; j > 0; j >>= 1) {
      for (int i = t; i < 2048; i += 256) {
        int ixj = i ^ j;
        if (ixj > i) {
          float a = srt[i], c = srt[ixj];
          bool up = ((i & ksz) == 0);
          if ((a > c) == up) { srt[i] = c; srt[ixj] = a; }
        }
      }
      __syncthreads();
    }
  }
  float thr = srt[2048 - k];

  int cnt = 0;
  for (int i = t; i < 2048; i += 256) cnt += (vals[i] > thr) ? 1 : 0;
  redi[t] = cnt;
  __syncthreads();
  for (int s = 128; s > 0; s >>= 1) {
    if (t < s) redi[t] += redi[t + s];
    __syncthreads();
  }
  int n_gt = redi[0];
  int need = k - n_gt;

  for (int i = t; i < 2048; i += 256) {
    float v = vals[i];
    float m = 0.f;
    if (v > thr) m = 1.f;
    else if (v == thr) {
      int pre = 0;
      for (int p = 0; p < i; ++p) pre += (vals[p] == thr) ? 1 : 0;
      if (pre < need) m = 1.f;
    }
    mask_out[(size_t)b * 2048 + i] = m;
  }
}

// ---------------- filtered = x * mask ----------------
__global__ void filter_k(const float4* __restrict__ x, const float* __restrict__ mask,
                         float4* __restrict__ out, int n4) {
  int stride = gridDim.x * blockDim.x;
  for (int i = blockIdx.x * blockDim.x + threadIdx.x; i < n4; i += stride) {
    float m = mask[i >> 9];
    float4 v = x[i];
    v.x *= m; v.y *= m; v.z *= m; v.w *= m;
    out[i] = v;
  }
}

extern "C" void kernel_launch(void* const* d_in, const int* in_sizes, int n_in,
                              void* d_out, int out_size, void* d_ws, size_t ws_size,
                              hipStream_t stream) {
  const float* x  = (const float*)d_in[0];
  const float* w1 = (const float*)d_in[1];
  const float* b1 = (const float*)d_in[2];
  const float* w2 = (const float*)d_in[3];
  const float* b2 = (const float*)d_in[4];

  float* out_filt = (float*)d_out;
  float* out_mask = out_filt + (size_t)67108864;
  float* out_ek   = out_mask + 32768;

  unsigned short* xhi = (unsigned short*)d_out;   // parked in out0 region

  char* wsb = (char*)d_ws;
  unsigned short* xlo  = (unsigned short*)wsb;                      // 134217728 B
  unsigned short* wthi = (unsigned short*)(wsb + 134217728);        // 8388608 B
  unsigned short* wtlo = (unsigned short*)(wsb + 142606336);        // 8388608 B
  float* part   = (float*)(wsb + 150994944);                        // 1048576 B used

  split_x_kernel<<<dim3(4096), dim3(256), 0, stream>>>(
      (const float4*)x, (ushort4*)xhi, (ushort4*)xlo, 16777216);
  split_wT_kernel<<<dim3(64, 64), dim3(32, 8), 0, stream>>>(w1, wthi, wtlo);
  gemm8<<<dim3(1024), dim3(512), 0, stream>>>(
      xhi, xlo, wthi, wtlo, b1, w2, part);
  rowstats<<<dim3(16), dim3(256), 0, stream>>>(part, b2, out_mask, out_ek);
  filter_k<<<dim3(4096), dim3(256), 0, stream>>>(
      (const float4*)x, out_mask, (float4*)out_filt, 16777216);
}